// Round 1
// baseline (552.438 us; speedup 1.0000x reference)
//
#include <hip/hip_runtime.h>
#include <math.h>

#define ROWS 18496          // bt*J*N = 64*17*17
#define SCALE 0.17677669529663687f  // 1/sqrt(32)

__device__ __forceinline__ void fma4(float4& d, float s, const float4& v) {
    d.x = fmaf(s, v.x, d.x); d.y = fmaf(s, v.y, d.y);
    d.z = fmaf(s, v.z, d.z); d.w = fmaf(s, v.w, d.w);
}

// ---------------- K1: qkv GEMM (18496x256 @ 256x1280) + M-scale + 5-way split
__global__ __launch_bounds__(256) void k_qkv(
    const float* __restrict__ x, const float* __restrict__ Wqkv,
    const float* __restrict__ M,
    float* __restrict__ q, float* __restrict__ k, float* __restrict__ vs,
    float* __restrict__ vv, float* __restrict__ vsv)
{
    __shared__ __align__(16) float As[8][132];
    __shared__ __align__(16) float Bs[8][132];
    const int t  = threadIdx.x;
    const int tx = t & 15, ty = t >> 4;
    const int m0 = blockIdx.y * 128;
    const int n0 = blockIdx.x * 128;

    float acc[8][8];
#pragma unroll
    for (int i = 0; i < 8; ++i)
#pragma unroll
        for (int j = 0; j < 8; ++j) acc[i][j] = 0.f;

    const int lrow = t >> 1;
    const int lkq  = (t & 1) * 4;
    int arow = m0 + lrow; if (arow > ROWS - 1) arow = ROWS - 1;
    const int bk = t >> 5, bn4 = (t & 31) * 4;

    for (int kb = 0; kb < 256; kb += 8) {
        float4 a4 = *(const float4*)&x[(size_t)arow * 256 + kb + lkq];
        float4 b4 = *(const float4*)&Wqkv[(size_t)(kb + bk) * 1280 + n0 + bn4];
        __syncthreads();
        As[lkq + 0][lrow] = a4.x; As[lkq + 1][lrow] = a4.y;
        As[lkq + 2][lrow] = a4.z; As[lkq + 3][lrow] = a4.w;
        *(float4*)&Bs[bk][bn4] = b4;
        __syncthreads();
#pragma unroll
        for (int kk = 0; kk < 8; ++kk) {
            float4 a0 = *(const float4*)&As[kk][ty * 8];
            float4 a1 = *(const float4*)&As[kk][ty * 8 + 4];
            float4 b0 = *(const float4*)&Bs[kk][tx * 8];
            float4 b1 = *(const float4*)&Bs[kk][tx * 8 + 4];
            float av[8] = {a0.x, a0.y, a0.z, a0.w, a1.x, a1.y, a1.z, a1.w};
            float bv[8] = {b0.x, b0.y, b0.z, b0.w, b1.x, b1.y, b1.z, b1.w};
#pragma unroll
            for (int i = 0; i < 8; ++i)
#pragma unroll
                for (int j = 0; j < 8; ++j)
                    acc[i][j] = fmaf(av[i], bv[j], acc[i][j]);
        }
    }

#pragma unroll
    for (int i = 0; i < 8; ++i) {
        int r = m0 + ty * 8 + i;
        if (r >= ROWS) continue;
        int n_ = r % 17, j_ = (r / 17) % 17;
        const float* Mrow = &M[(size_t)(j_ * 17 + n_) * 256];
#pragma unroll
        for (int j = 0; j < 8; ++j) {
            int o = n0 + tx * 8 + j;
            int which = o % 5, cc = o / 5;
            float* dst = q;
            if (which == 1) dst = k;
            else if (which == 2) dst = vs;
            else if (which == 3) dst = vv;
            else if (which == 4) dst = vsv;
            dst[(size_t)r * 256 + cc] = acc[i][j] * Mrow[cc];
        }
    }
}

// ---------------- K2a: attention scores + 4 softmaxes --------------------
// grid = 512*17 ; block bx: bh = bx/17, slice i = bx%17.
// part S: n=i, rows j over kj ; part V: j=i, rows n over m.
__global__ __launch_bounds__(256) void k_scores(
    const float* __restrict__ q, const float* __restrict__ k,
    const float* __restrict__ A_s, const float* __restrict__ A_v,
    const float* __restrict__ adjS, const float* __restrict__ adjV,
    float* __restrict__ attS, float* __restrict__ attV,
    float* __restrict__ attS2, float* __restrict__ attV2)
{
    __shared__ __align__(16) float qsh[544];
    __shared__ __align__(16) float ksh[544];
    __shared__ __align__(16) float rawsh[289];
    const int t  = threadIdx.x;
    const int bh = blockIdx.x / 17;
    const int i  = blockIdx.x % 17;
    const int b  = bh >> 3, h = bh & 7;

    // ======== part S (n = i) ========
    for (int idx = t; idx < 272; idx += 256) {
        int w = idx / 136, rem = idx % 136;
        int row = rem >> 3, c4 = (rem & 7) * 4;
        const float* src = w ? k : q;
        float* dst = w ? ksh : qsh;
        *(float4*)&dst[row * 32 + c4] =
            *(const float4*)&src[(((size_t)b * 17 + row) * 17 + i) * 256 + h * 32 + c4];
    }
    __syncthreads();
    for (int idx = t; idx < 289; idx += 256) {
        int jj = idx / 17, kk = idx % 17;
        float s = 0.f;
#pragma unroll
        for (int c = 0; c < 32; c += 4) {
            float4 qv = *(const float4*)&qsh[jj * 32 + c];
            float4 kv = *(const float4*)&ksh[kk * 32 + c];
            s += qv.x * kv.x + qv.y * kv.y + qv.z * kv.z + qv.w * kv.w;
        }
        rawsh[idx] = s * SCALE;
    }
    __syncthreads();
    if (t < 34) {
        int jj = t % 17, biased = t / 17;
        float v[17];
#pragma unroll
        for (int kk = 0; kk < 17; ++kk) {
            float s = rawsh[jj * 17 + kk];
            if (biased)
                s += 0.5f * ((A_s[jj*17+kk] + adjS[jj*17+kk]) + (A_s[kk*17+jj] + adjS[kk*17+jj]));
            v[kk] = s;
        }
        float mx = v[0];
#pragma unroll
        for (int kk = 1; kk < 17; ++kk) mx = fmaxf(mx, v[kk]);
        float sum = 0.f;
#pragma unroll
        for (int kk = 0; kk < 17; ++kk) { v[kk] = expf(v[kk] - mx); sum += v[kk]; }
        float inv = 1.f / sum;
        float* dst = biased ? attS2 : attS;
        size_t base = (((size_t)bh * 17 + i) * 17 + jj) * 17;
#pragma unroll
        for (int kk = 0; kk < 17; ++kk) dst[base + kk] = v[kk] * inv;
    }
    __syncthreads();

    // ======== part V (j = i) ========
    for (int idx = t; idx < 272; idx += 256) {
        int w = idx / 136, rem = idx % 136;
        int row = rem >> 3, c4 = (rem & 7) * 4;
        const float* src = w ? k : q;
        float* dst = w ? ksh : qsh;
        *(float4*)&dst[row * 32 + c4] =
            *(const float4*)&src[(((size_t)b * 17 + i) * 17 + row) * 256 + h * 32 + c4];
    }
    __syncthreads();
    for (int idx = t; idx < 289; idx += 256) {
        int nn = idx / 17, mm = idx % 17;
        float s = 0.f;
#pragma unroll
        for (int c = 0; c < 32; c += 4) {
            float4 qv = *(const float4*)&qsh[nn * 32 + c];
            float4 kv = *(const float4*)&ksh[mm * 32 + c];
            s += qv.x * kv.x + qv.y * kv.y + qv.z * kv.z + qv.w * kv.w;
        }
        rawsh[idx] = s * SCALE;
    }
    __syncthreads();
    if (t < 34) {
        int nn = t % 17, biased = t / 17;
        float v[17];
#pragma unroll
        for (int mm = 0; mm < 17; ++mm) {
            float s = rawsh[nn * 17 + mm];
            if (biased)
                s += 0.5f * ((A_v[nn*17+mm] + adjV[nn*17+mm]) + (A_v[mm*17+nn] + adjV[mm*17+nn]));
            v[mm] = s;
        }
        float mx = v[0];
#pragma unroll
        for (int mm = 1; mm < 17; ++mm) mx = fmaxf(mx, v[mm]);
        float sum = 0.f;
#pragma unroll
        for (int mm = 0; mm < 17; ++mm) { v[mm] = expf(v[mm] - mx); sum += v[mm]; }
        float inv = 1.f / sum;
        float* dst = biased ? attV2 : attV;
        size_t base = (((size_t)bh * 17 + i) * 17 + nn) * 17;
#pragma unroll
        for (int mm = 0; mm < 17; ++mm) dst[base + mm] = v[mm] * inv;
    }
}

// ---------------- K2b: x_vs and x_vv -> y cols 256..767 ------------------
__global__ __launch_bounds__(256) void k_xvs_xvv(
    const float* __restrict__ vs, const float* __restrict__ vv,
    const float* __restrict__ attS2, const float* __restrict__ attV2,
    float* __restrict__ y)
{
    __shared__ __align__(16) float att2[4913];
    __shared__ __align__(16) float vbuf[9248];
    const int t  = threadIdx.x;
    const int bh = blockIdx.x;
    const int b  = bh >> 3, h = bh & 7;
    const int pq = t >> 3, c4 = (t & 7) * 4;

    // phase 1: x_vs[j,n,c] = sum_k attS2[n,j,k] * vs[k,n,c]
    for (int idx = t; idx < 4913; idx += 256) att2[idx] = attS2[(size_t)bh * 4913 + idx];
    for (int idx = t; idx < 2312; idx += 256) {
        int p = idx >> 3, cc = (idx & 7) * 4;
        *(float4*)&vbuf[p * 32 + cc] =
            *(const float4*)&vs[(((size_t)b * 17 + p / 17) * 17 + p % 17) * 256 + h * 32 + cc];
    }
    __syncthreads();
    for (int pi = 0; pi < 10; ++pi) {
        int p = pi * 32 + pq;
        if (p < 289) {
            int j = p / 17, n = p % 17;
            const float* arow = &att2[(n * 17 + j) * 17];
            float4 acc = {0,0,0,0};
            for (int kk = 0; kk < 17; ++kk) {
                float4 v = *(const float4*)&vbuf[(kk * 17 + n) * 32 + c4];
                fma4(acc, arow[kk], v);
            }
            size_t r = ((size_t)b * 17 + j) * 17 + n;
            *(float4*)&y[r * 768 + 256 + h * 32 + c4] = acc;
        }
    }
    __syncthreads();
    // phase 2: x_vv[j,n,c] = sum_m attV2[j,n,m] * vv[j,m,c]
    for (int idx = t; idx < 4913; idx += 256) att2[idx] = attV2[(size_t)bh * 4913 + idx];
    for (int idx = t; idx < 2312; idx += 256) {
        int p = idx >> 3, cc = (idx & 7) * 4;
        *(float4*)&vbuf[p * 32 + cc] =
            *(const float4*)&vv[(((size_t)b * 17 + p / 17) * 17 + p % 17) * 256 + h * 32 + cc];
    }
    __syncthreads();
    for (int pi = 0; pi < 10; ++pi) {
        int p = pi * 32 + pq;
        if (p < 289) {
            int j = p / 17, n = p % 17;
            const float* arow = &att2[(j * 17 + n) * 17];
            float4 acc = {0,0,0,0};
            for (int mm = 0; mm < 17; ++mm) {
                float4 v = *(const float4*)&vbuf[(j * 17 + mm) * 32 + c4];
                fma4(acc, arow[mm], v);
            }
            size_t r = ((size_t)b * 17 + j) * 17 + n;
            *(float4*)&y[r * 768 + 512 + h * 32 + c4] = acc;
        }
    }
}

// ---------------- K2c: x_vsv (bilinear combine) -> y cols 0..255 ---------
__global__ __launch_bounds__(256) void k_xvsv(
    const float* __restrict__ vsv, const float* __restrict__ attS,
    const float* __restrict__ attV, float* __restrict__ y)
{
    __shared__ __align__(16) float vbuf[9248];   // [k][m][c] for this (b,h)
    const int t  = threadIdx.x;
    const int bh = blockIdx.x;
    const int b  = bh >> 3, h = bh & 7;
    const int pq = t >> 3, c4 = (t & 7) * 4;
    const float* aSg = attS + (size_t)bh * 4913;  // [n][j][k]
    const float* aVg = attV + (size_t)bh * 4913;  // [j][n][m]

    for (int idx = t; idx < 2312; idx += 256) {
        int p = idx >> 3, cc = (idx & 7) * 4;
        *(float4*)&vbuf[p * 32 + cc] =
            *(const float4*)&vsv[(((size_t)b * 17 + p / 17) * 17 + p % 17) * 256 + h * 32 + cc];
    }
    __syncthreads();

    for (int pi = 0; pi < 5; ++pi) {
        int p0 = pi * 64 + pq;
        int p1 = p0 + 32;
        bool hasp1 = (p1 < 289);
        int p1c = hasp1 ? p1 : 0;
        int j0 = p0 / 17, n0 = p0 % 17;
        int j1 = p1c / 17, n1 = p1c % 17;
        float b0r[17], b1r[17];
        const float* bv0 = &aVg[(j0 * 17 + n0) * 17];
        const float* bv1 = &aVg[(j1 * 17 + n1) * 17];
#pragma unroll
        for (int m = 0; m < 17; ++m) { b0r[m] = bv0[m]; b1r[m] = bv1[m]; }
        const float* ap0 = &aSg[(n0 * 17 + j0) * 17];
        const float* ap1 = &aSg[(n1 * 17 + j1) * 17];
        float4 acc0 = {0,0,0,0}, acc1 = {0,0,0,0};
        for (int kk = 0; kk < 17; ++kk) {
            float a0 = ap0[kk], a1 = ap1[kk];
            float4 t0 = {0,0,0,0}, t1 = {0,0,0,0};
            const float* vrow = &vbuf[kk * 544 + c4];
#pragma unroll
            for (int m = 0; m < 17; ++m) {
                float4 v = *(const float4*)&vrow[m * 32];
                fma4(t0, b0r[m], v);
                fma4(t1, b1r[m], v);
            }
            fma4(acc0, a0, t0);
            fma4(acc1, a1, t1);
        }
        size_t r0 = ((size_t)b * 17 + j0) * 17 + n0;
        *(float4*)&y[r0 * 768 + h * 32 + c4] = acc0;
        if (hasp1) {
            size_t r1 = ((size_t)b * 17 + j1) * 17 + n1;
            *(float4*)&y[r1 * 768 + h * 32 + c4] = acc1;
        }
    }
}

// ---------------- K3: proj GEMM (18496x768 @ 768x256) + bias -------------
__global__ __launch_bounds__(256) void k_proj(
    const float* __restrict__ y, const float* __restrict__ Wp,
    const float* __restrict__ bp, float* __restrict__ out)
{
    __shared__ __align__(16) float As[8][132];
    __shared__ __align__(16) float Bs[8][68];
    const int t  = threadIdx.x;
    const int tx = t & 15, ty = t >> 4;
    const int m0 = blockIdx.y * 128, n0 = blockIdx.x * 64;

    float acc[8][4];
#pragma unroll
    for (int i = 0; i < 8; ++i)
#pragma unroll
        for (int j = 0; j < 4; ++j) acc[i][j] = 0.f;

    const int lrow = t >> 1, lkq = (t & 1) * 4;
    int arow = m0 + lrow; if (arow > ROWS - 1) arow = ROWS - 1;
    const int wk = t >> 4, wn4 = (t & 15) * 4;

    for (int kb = 0; kb < 768; kb += 8) {
        float4 a4 = *(const float4*)&y[(size_t)arow * 768 + kb + lkq];
        float4 b4 = {0,0,0,0};
        if (t < 128) b4 = *(const float4*)&Wp[(size_t)(kb + wk) * 256 + n0 + wn4];
        __syncthreads();
        As[lkq + 0][lrow] = a4.x; As[lkq + 1][lrow] = a4.y;
        As[lkq + 2][lrow] = a4.z; As[lkq + 3][lrow] = a4.w;
        if (t < 128) *(float4*)&Bs[wk][wn4] = b4;
        __syncthreads();
#pragma unroll
        for (int kk = 0; kk < 8; ++kk) {
            float4 a0 = *(const float4*)&As[kk][ty * 8];
            float4 a1 = *(const float4*)&As[kk][ty * 8 + 4];
            float4 b0 = *(const float4*)&Bs[kk][tx * 4];
            float av[8] = {a0.x, a0.y, a0.z, a0.w, a1.x, a1.y, a1.z, a1.w};
#pragma unroll
            for (int i = 0; i < 8; ++i) {
                acc[i][0] = fmaf(av[i], b0.x, acc[i][0]);
                acc[i][1] = fmaf(av[i], b0.y, acc[i][1]);
                acc[i][2] = fmaf(av[i], b0.z, acc[i][2]);
                acc[i][3] = fmaf(av[i], b0.w, acc[i][3]);
            }
        }
    }
    float4 bias = *(const float4*)&bp[n0 + tx * 4];
#pragma unroll
    for (int i = 0; i < 8; ++i) {
        int r = m0 + ty * 8 + i;
        if (r >= ROWS) continue;
        float4 o;
        o.x = acc[i][0] + bias.x; o.y = acc[i][1] + bias.y;
        o.z = acc[i][2] + bias.z; o.w = acc[i][3] + bias.w;
        *(float4*)&out[(size_t)r * 256 + n0 + tx * 4] = o;
    }
}

extern "C" void kernel_launch(void* const* d_in, const int* in_sizes, int n_in,
                              void* d_out, int out_size, void* d_ws, size_t ws_size,
                              hipStream_t stream)
{
    const float* x    = (const float*)d_in[0];
    const float* A_s  = (const float*)d_in[1];
    const float* A_v  = (const float*)d_in[2];
    const float* Wqkv = (const float*)d_in[3];
    const float* Wp   = (const float*)d_in[4];
    const float* bp   = (const float*)d_in[5];
    const float* M    = (const float*)d_in[6];
    const float* adjS = (const float*)d_in[7];
    const float* adjV = (const float*)d_in[8];
    float* out = (float*)d_out;

    const size_t TEN = 4734976;   // 64*17*17*256
    const size_t ATT = 2515456;   // 512*17*17*17
    float* ws   = (float*)d_ws;
    float* q    = ws;
    float* k    = ws + 1 * TEN;
    float* vs   = ws + 2 * TEN;
    float* vv   = ws + 3 * TEN;
    float* vsv  = ws + 4 * TEN;
    float* attS  = ws + 5 * TEN;
    float* attV  = ws + 5 * TEN + 1 * ATT;
    float* attS2 = ws + 5 * TEN + 2 * ATT;
    float* attV2 = ws + 5 * TEN + 3 * ATT;
    float* y     = ws + 5 * TEN + 4 * ATT;   // 18496*768

    k_qkv<<<dim3(10, 145), 256, 0, stream>>>(x, Wqkv, M, q, k, vs, vv, vsv);
    k_scores<<<dim3(512 * 17), 256, 0, stream>>>(q, k, A_s, A_v, adjS, adjV,
                                                 attS, attV, attS2, attV2);
    k_xvs_xvv<<<dim3(512), 256, 0, stream>>>(vs, vv, attS2, attV2, y);
    k_xvsv<<<dim3(512), 256, 0, stream>>>(vsv, attS, attV, y);
    k_proj<<<dim3(4, 145), 256, 0, stream>>>(y, Wp, bp, out);
}

// Round 2
// 338.522 us; speedup vs baseline: 1.6319x; 1.6319x over previous
//
#include <hip/hip_runtime.h>
#include <math.h>

#define ROWS 18496          // bt*J*N = 64*17*17
#define SCALE 0.17677669529663687f  // 1/sqrt(32)

typedef unsigned short ushort_t;
typedef __attribute__((ext_vector_type(8))) short short8;
typedef __attribute__((ext_vector_type(4))) float f32x4;

__device__ __forceinline__ void fma4(float4& d, float s, const float4& v) {
    d.x = fmaf(s, v.x, d.x); d.y = fmaf(s, v.y, d.y);
    d.z = fmaf(s, v.z, d.z); d.w = fmaf(s, v.w, d.w);
}

__device__ __forceinline__ ushort_t f2bf(float x) {
    union { float f; unsigned u; } v; v.f = x;
    unsigned r = v.u + 0x7fffu + ((v.u >> 16) & 1u);
    return (ushort_t)(r >> 16);
}
__device__ __forceinline__ float bf2f(ushort_t b) {
    union { unsigned u; float f; } v; v.u = ((unsigned)b) << 16; return v.f;
}

__device__ __forceinline__ void gl_lds16(const void* g, void* l) {
    __builtin_amdgcn_global_load_lds(
        (const __attribute__((address_space(1))) void*)g,
        (__attribute__((address_space(3))) void*)l, 16, 0, 0);
}

// ---------------- conversion kernels ----------------------------------
// x (18496x256 f32) -> xhi/xlo bf16
__global__ __launch_bounds__(256) void k_cvt_x(
    const float4* __restrict__ x, ushort4* __restrict__ xhi, ushort4* __restrict__ xlo)
{
    int i = blockIdx.x * 256 + threadIdx.x;   // over 1183744 float4s
    float4 v = x[i];
    ushort4 h, l;
    h.x = f2bf(v.x); l.x = f2bf(v.x - bf2f(h.x));
    h.y = f2bf(v.y); l.y = f2bf(v.y - bf2f(h.y));
    h.z = f2bf(v.z); l.z = f2bf(v.z - bf2f(h.z));
    h.w = f2bf(v.w); l.w = f2bf(v.w - bf2f(h.w));
    xhi[i] = h; xlo[i] = l;
}

// Wqkv (256x1280 f32) -> transposed+permuted bf16 [o][k], o: which*256+cc maps to col cc*5+which
__global__ __launch_bounds__(256) void k_cvt_wqkv(
    const float* __restrict__ W, ushort_t* __restrict__ bh, ushort_t* __restrict__ bl)
{
    int o = blockIdx.x;          // 0..1279
    int kk = threadIdx.x;        // 0..255
    int col = (o & 255) * 5 + (o >> 8);
    float v = W[(size_t)kk * 1280 + col];
    ushort_t h = f2bf(v);
    bh[(size_t)o * 256 + kk] = h;
    bl[(size_t)o * 256 + kk] = f2bf(v - bf2f(h));
}

// Wp (768x256 f32) -> transposed bf16 [n][k]
__global__ __launch_bounds__(256) void k_cvt_wp(
    const float* __restrict__ W, ushort_t* __restrict__ bh, ushort_t* __restrict__ bl)
{
    int n = blockIdx.x;          // 0..255
    for (int k = threadIdx.x; k < 768; k += 256) {
        float v = W[(size_t)k * 256 + n];
        ushort_t h = f2bf(v);
        bh[(size_t)n * 768 + k] = h;
        bl[(size_t)n * 768 + k] = f2bf(v - bf2f(h));
    }
}

// ---------------- split-bf16 MFMA GEMM --------------------------------
// A: [ROWS][K] bf16 hi/lo row-major. B: [N][K] bf16 hi/lo (transposed).
// C = Ahi*Bhi + Ahi*Blo + Alo*Bhi.
// MODE 0 (qkv): out[gm*1280+gn] = acc * M[(gm%289)*256 + (gn&255)]
// MODE 1 (proj): out[gm*256+gn]  = acc + bias[gn]
template<int BM, int BN, int K, int MODE>
__global__ __launch_bounds__(256) void k_gemm(
    const ushort_t* __restrict__ Ahi, const ushort_t* __restrict__ Alo,
    const ushort_t* __restrict__ Bhi, const ushort_t* __restrict__ Blo,
    const float* __restrict__ aux,   // M mask (MODE 0) or bias (MODE 1)
    float* __restrict__ out)
{
    constexpr int MT = BM / 32;      // m-tiles per wave (2x2 wave grid)
    constexpr int NT = BN / 32;      // n-tiles per wave
    __shared__ __attribute__((aligned(16))) ushort_t sAh[BM * 32];
    __shared__ __attribute__((aligned(16))) ushort_t sAl[BM * 32];
    __shared__ __attribute__((aligned(16))) ushort_t sBh[BN * 32];
    __shared__ __attribute__((aligned(16))) ushort_t sBl[BN * 32];

    const int t = threadIdx.x;
    const int lane = t & 63;
    const int ln = lane & 15, quad = lane >> 4;
    const int wave = t >> 6;
    const int wm = wave >> 1, wn = wave & 1;
    const int m0 = blockIdx.y * BM, n0 = blockIdx.x * BN;

    f32x4 acc[MT][NT];
#pragma unroll
    for (int i = 0; i < MT; ++i)
#pragma unroll
        for (int j = 0; j < NT; ++j) acc[i][j] = (f32x4){0.f, 0.f, 0.f, 0.f};

    for (int kb = 0; kb < K; kb += 32) {
        __syncthreads();
#pragma unroll
        for (int s = t; s < BM * 4; s += 256) {       // A tiles: BM rows x 64B
            int row = s >> 2, kc = s & 3;
            int gr = m0 + row; if (gr > ROWS - 1) gr = ROWS - 1;
            size_t gb = ((size_t)gr * K + kb) * 2 + kc * 16;
            int lb = (s & ~63) * 16;
            gl_lds16((const char*)Ahi + gb, (char*)sAh + lb);
            gl_lds16((const char*)Alo + gb, (char*)sAl + lb);
        }
#pragma unroll
        for (int s = t; s < BN * 4; s += 256) {       // B tiles: BN rows x 64B
            int row = s >> 2, kc = s & 3;
            size_t gb = ((size_t)(n0 + row) * K + kb) * 2 + kc * 16;
            int lb = (s & ~63) * 16;
            gl_lds16((const char*)Bhi + gb, (char*)sBh + lb);
            gl_lds16((const char*)Blo + gb, (char*)sBl + lb);
        }
        __syncthreads();

        short8 ah[MT], al[MT], bh[NT], bl[NT];
#pragma unroll
        for (int i = 0; i < MT; ++i) {
            int off = (wm * (BM / 2) + i * 16 + ln) * 32 + quad * 8;
            ah[i] = *(const short8*)&sAh[off];
            al[i] = *(const short8*)&sAl[off];
        }
#pragma unroll
        for (int j = 0; j < NT; ++j) {
            int off = (wn * (BN / 2) + j * 16 + ln) * 32 + quad * 8;
            bh[j] = *(const short8*)&sBh[off];
            bl[j] = *(const short8*)&sBl[off];
        }
#pragma unroll
        for (int i = 0; i < MT; ++i)
#pragma unroll
            for (int j = 0; j < NT; ++j) {
                acc[i][j] = __builtin_amdgcn_mfma_f32_16x16x32_bf16(ah[i], bh[j], acc[i][j], 0, 0, 0);
                acc[i][j] = __builtin_amdgcn_mfma_f32_16x16x32_bf16(ah[i], bl[j], acc[i][j], 0, 0, 0);
                acc[i][j] = __builtin_amdgcn_mfma_f32_16x16x32_bf16(al[i], bh[j], acc[i][j], 0, 0, 0);
            }
    }

    // epilogue: C/D layout col=lane&15, row=quad*4+reg (m89/m91-verified)
#pragma unroll
    for (int i = 0; i < MT; ++i) {
#pragma unroll
        for (int r = 0; r < 4; ++r) {
            int gm = m0 + wm * (BM / 2) + i * 16 + quad * 4 + r;
            if (gm >= ROWS) continue;
            if (MODE == 0) {
                int jn = gm % 289;
                const float* Mrow = &aux[(size_t)jn * 256];
#pragma unroll
                for (int j = 0; j < NT; ++j) {
                    int gn = n0 + wn * (BN / 2) + j * 16 + ln;
                    out[(size_t)gm * 1280 + gn] = acc[i][j][r] * Mrow[gn & 255];
                }
            } else {
#pragma unroll
                for (int j = 0; j < NT; ++j) {
                    int gn = n0 + wn * (BN / 2) + j * 16 + ln;
                    out[(size_t)gm * 256 + gn] = acc[i][j][r] + aux[gn];
                }
            }
        }
    }
}

// ---------------- K2a: attention scores + 4 softmaxes --------------------
// qkv5 layout: [row][1280], cols 0..255=q, 256..511=k, 512..767=vs, 768..1023=vv, 1024..1279=vsv
__global__ __launch_bounds__(256) void k_scores(
    const float* __restrict__ qkv5,
    const float* __restrict__ A_s, const float* __restrict__ A_v,
    const float* __restrict__ adjS, const float* __restrict__ adjV,
    float* __restrict__ attS, float* __restrict__ attV,
    float* __restrict__ attS2, float* __restrict__ attV2)
{
    __shared__ __attribute__((aligned(16))) float qsh[544];
    __shared__ __attribute__((aligned(16))) float ksh[544];
    __shared__ __attribute__((aligned(16))) float rawsh[289];
    const int t  = threadIdx.x;
    const int bh = blockIdx.x / 17;
    const int i  = blockIdx.x % 17;
    const int b  = bh >> 3, h = bh & 7;

    // ======== part S (n = i) ========
    for (int idx = t; idx < 272; idx += 256) {
        int w = idx / 136, rem = idx % 136;
        int row = rem >> 3, c4 = (rem & 7) * 4;
        float* dst = w ? ksh : qsh;
        int woff = w ? 256 : 0;
        *(float4*)&dst[row * 32 + c4] =
            *(const float4*)&qkv5[(((size_t)b * 17 + row) * 17 + i) * 1280 + woff + h * 32 + c4];
    }
    __syncthreads();
    for (int idx = t; idx < 289; idx += 256) {
        int jj = idx / 17, kk = idx % 17;
        float s = 0.f;
#pragma unroll
        for (int c = 0; c < 32; c += 4) {
            float4 qv = *(const float4*)&qsh[jj * 32 + c];
            float4 kv = *(const float4*)&ksh[kk * 32 + c];
            s += qv.x * kv.x + qv.y * kv.y + qv.z * kv.z + qv.w * kv.w;
        }
        rawsh[idx] = s * SCALE;
    }
    __syncthreads();
    if (t < 34) {
        int jj = t % 17, biased = t / 17;
        float v[17];
#pragma unroll
        for (int kk = 0; kk < 17; ++kk) {
            float s = rawsh[jj * 17 + kk];
            if (biased)
                s += 0.5f * ((A_s[jj*17+kk] + adjS[jj*17+kk]) + (A_s[kk*17+jj] + adjS[kk*17+jj]));
            v[kk] = s;
        }
        float mx = v[0];
#pragma unroll
        for (int kk = 1; kk < 17; ++kk) mx = fmaxf(mx, v[kk]);
        float sum = 0.f;
#pragma unroll
        for (int kk = 0; kk < 17; ++kk) { v[kk] = expf(v[kk] - mx); sum += v[kk]; }
        float inv = 1.f / sum;
        float* dst = biased ? attS2 : attS;
        size_t base = (((size_t)bh * 17 + i) * 17 + jj) * 17;
#pragma unroll
        for (int kk = 0; kk < 17; ++kk) dst[base + kk] = v[kk] * inv;
    }
    __syncthreads();

    // ======== part V (j = i) ========
    for (int idx = t; idx < 272; idx += 256) {
        int w = idx / 136, rem = idx % 136;
        int row = rem >> 3, c4 = (rem & 7) * 4;
        float* dst = w ? ksh : qsh;
        int woff = w ? 256 : 0;
        *(float4*)&dst[row * 32 + c4] =
            *(const float4*)&qkv5[(((size_t)b * 17 + i) * 17 + row) * 1280 + woff + h * 32 + c4];
    }
    __syncthreads();
    for (int idx = t; idx < 289; idx += 256) {
        int nn = idx / 17, mm = idx % 17;
        float s = 0.f;
#pragma unroll
        for (int c = 0; c < 32; c += 4) {
            float4 qv = *(const float4*)&qsh[nn * 32 + c];
            float4 kv = *(const float4*)&ksh[mm * 32 + c];
            s += qv.x * kv.x + qv.y * kv.y + qv.z * kv.z + qv.w * kv.w;
        }
        rawsh[idx] = s * SCALE;
    }
    __syncthreads();
    if (t < 34) {
        int nn = t % 17, biased = t / 17;
        float v[17];
#pragma unroll
        for (int mm = 0; mm < 17; ++mm) {
            float s = rawsh[nn * 17 + mm];
            if (biased)
                s += 0.5f * ((A_v[nn*17+mm] + adjV[nn*17+mm]) + (A_v[mm*17+nn] + adjV[mm*17+nn]));
            v[mm] = s;
        }
        float mx = v[0];
#pragma unroll
        for (int mm = 1; mm < 17; ++mm) mx = fmaxf(mx, v[mm]);
        float sum = 0.f;
#pragma unroll
        for (int mm = 0; mm < 17; ++mm) { v[mm] = expf(v[mm] - mx); sum += v[mm]; }
        float inv = 1.f / sum;
        float* dst = biased ? attV2 : attV;
        size_t base = (((size_t)bh * 17 + i) * 17 + nn) * 17;
#pragma unroll
        for (int mm = 0; mm < 17; ++mm) dst[base + mm] = v[mm] * inv;
    }
}

__device__ __forceinline__ void store_hilo(ushort_t* yhi, ushort_t* ylo,
                                           size_t off, const float4& a)
{
    ushort4 h, l;
    h.x = f2bf(a.x); l.x = f2bf(a.x - bf2f(h.x));
    h.y = f2bf(a.y); l.y = f2bf(a.y - bf2f(h.y));
    h.z = f2bf(a.z); l.z = f2bf(a.z - bf2f(h.z));
    h.w = f2bf(a.w); l.w = f2bf(a.w - bf2f(h.w));
    *(ushort4*)&yhi[off] = h;
    *(ushort4*)&ylo[off] = l;
}

// ---------------- K2b: x_vs and x_vv -> y cols 256..767 (bf16 hi/lo) -----
__global__ __launch_bounds__(256) void k_xvs_xvv(
    const float* __restrict__ qkv5,
    const float* __restrict__ attS2, const float* __restrict__ attV2,
    ushort_t* __restrict__ yhi, ushort_t* __restrict__ ylo)
{
    __shared__ __attribute__((aligned(16))) float att2[4913];
    __shared__ __attribute__((aligned(16))) float vbuf[9248];
    const int t  = threadIdx.x;
    const int bh = blockIdx.x;
    const int b  = bh >> 3, h = bh & 7;
    const int pq = t >> 3, c4 = (t & 7) * 4;

    // phase 1: x_vs[j,n,c] = sum_k attS2[n,j,k] * vs[k,n,c]
    for (int idx = t; idx < 4913; idx += 256) att2[idx] = attS2[(size_t)bh * 4913 + idx];
    for (int idx = t; idx < 2312; idx += 256) {
        int p = idx >> 3, cc = (idx & 7) * 4;
        *(float4*)&vbuf[p * 32 + cc] =
            *(const float4*)&qkv5[(((size_t)b * 17 + p / 17) * 17 + p % 17) * 1280 + 512 + h * 32 + cc];
    }
    __syncthreads();
    for (int pi = 0; pi < 10; ++pi) {
        int p = pi * 32 + pq;
        if (p < 289) {
            int j = p / 17, n = p % 17;
            const float* arow = &att2[(n * 17 + j) * 17];
            float4 acc = {0,0,0,0};
            for (int kk = 0; kk < 17; ++kk) {
                float4 v = *(const float4*)&vbuf[(kk * 17 + n) * 32 + c4];
                fma4(acc, arow[kk], v);
            }
            size_t r = ((size_t)b * 17 + j) * 17 + n;
            store_hilo(yhi, ylo, r * 768 + 256 + h * 32 + c4, acc);
        }
    }
    __syncthreads();
    // phase 2: x_vv[j,n,c] = sum_m attV2[j,n,m] * vv[j,m,c]
    for (int idx = t; idx < 4913; idx += 256) att2[idx] = attV2[(size_t)bh * 4913 + idx];
    for (int idx = t; idx < 2312; idx += 256) {
        int p = idx >> 3, cc = (idx & 7) * 4;
        *(float4*)&vbuf[p * 32 + cc] =
            *(const float4*)&qkv5[(((size_t)b * 17 + p / 17) * 17 + p % 17) * 1280 + 768 + h * 32 + cc];
    }
    __syncthreads();
    for (int pi = 0; pi < 10; ++pi) {
        int p = pi * 32 + pq;
        if (p < 289) {
            int j = p / 17, n = p % 17;
            const float* arow = &att2[(j * 17 + n) * 17];
            float4 acc = {0,0,0,0};
            for (int mm = 0; mm < 17; ++mm) {
                float4 v = *(const float4*)&vbuf[(j * 17 + mm) * 32 + c4];
                fma4(acc, arow[mm], v);
            }
            size_t r = ((size_t)b * 17 + j) * 17 + n;
            store_hilo(yhi, ylo, r * 768 + 512 + h * 32 + c4, acc);
        }
    }
}

// ---------------- K2c: x_vsv (bilinear combine) -> y cols 0..255 ---------
__global__ __launch_bounds__(256) void k_xvsv(
    const float* __restrict__ qkv5, const float* __restrict__ attS,
    const float* __restrict__ attV,
    ushort_t* __restrict__ yhi, ushort_t* __restrict__ ylo)
{
    __shared__ __attribute__((aligned(16))) float vbuf[9248];   // [k][m][c]
    const int t  = threadIdx.x;
    const int bh = blockIdx.x;
    const int b  = bh >> 3, h = bh & 7;
    const int pq = t >> 3, c4 = (t & 7) * 4;
    const float* aSg = attS + (size_t)bh * 4913;  // [n][j][k]
    const float* aVg = attV + (size_t)bh * 4913;  // [j][n][m]

    for (int idx = t; idx < 2312; idx += 256) {
        int p = idx >> 3, cc = (idx & 7) * 4;
        *(float4*)&vbuf[p * 32 + cc] =
            *(const float4*)&qkv5[(((size_t)b * 17 + p / 17) * 17 + p % 17) * 1280 + 1024 + h * 32 + cc];
    }
    __syncthreads();

    for (int pi = 0; pi < 5; ++pi) {
        int p0 = pi * 64 + pq;
        int p1 = p0 + 32;
        bool hasp1 = (p1 < 289);
        int p1c = hasp1 ? p1 : 0;
        int j0 = p0 / 17, n0 = p0 % 17;
        int j1 = p1c / 17, n1 = p1c % 17;
        float b0r[17], b1r[17];
        const float* bv0 = &aVg[(j0 * 17 + n0) * 17];
        const float* bv1 = &aVg[(j1 * 17 + n1) * 17];
#pragma unroll
        for (int m = 0; m < 17; ++m) { b0r[m] = bv0[m]; b1r[m] = bv1[m]; }
        const float* ap0 = &aSg[(n0 * 17 + j0) * 17];
        const float* ap1 = &aSg[(n1 * 17 + j1) * 17];
        float4 acc0 = {0,0,0,0}, acc1 = {0,0,0,0};
        for (int kk = 0; kk < 17; ++kk) {
            float a0 = ap0[kk], a1 = ap1[kk];
            float4 t0 = {0,0,0,0}, t1 = {0,0,0,0};
            const float* vrow = &vbuf[kk * 544 + c4];
#pragma unroll
            for (int m = 0; m < 17; ++m) {
                float4 v = *(const float4*)&vrow[m * 32];
                fma4(t0, b0r[m], v);
                fma4(t1, b1r[m], v);
            }
            fma4(acc0, a0, t0);
            fma4(acc1, a1, t1);
        }
        size_t r0 = ((size_t)b * 17 + j0) * 17 + n0;
        store_hilo(yhi, ylo, r0 * 768 + h * 32 + c4, acc0);
        if (hasp1) {
            size_t r1 = ((size_t)b * 17 + j1) * 17 + n1;
            store_hilo(yhi, ylo, r1 * 768 + h * 32 + c4, acc1);
        }
    }
}

extern "C" void kernel_launch(void* const* d_in, const int* in_sizes, int n_in,
                              void* d_out, int out_size, void* d_ws, size_t ws_size,
                              hipStream_t stream)
{
    const float* x    = (const float*)d_in[0];
    const float* A_s  = (const float*)d_in[1];
    const float* A_v  = (const float*)d_in[2];
    const float* Wqkv = (const float*)d_in[3];
    const float* Wp   = (const float*)d_in[4];
    const float* bp   = (const float*)d_in[5];
    const float* M    = (const float*)d_in[6];
    const float* adjS = (const float*)d_in[7];
    const float* adjV = (const float*)d_in[8];
    float* out = (float*)d_out;

    char* w = (char*)d_ws;
    // [0, 94699520): qkv5 fp32 [18496][1280]; also reused LATE for Wp_t hi/lo
    float*    qkv5  = (float*)w;
    ushort_t* wph   = (ushort_t*)w;                       // written after combines
    ushort_t* wpl   = (ushort_t*)(w + 393216);
    // [94699520, 134946816): 4 attention tensors, each 10061824 B
    float* attS  = (float*)(w + 94699520);
    float* attV  = (float*)(w + 94699520 + 10061824);
    float* attS2 = (float*)(w + 94699520 + 2 * (size_t)10061824);
    float* attV2 = (float*)(w + 94699520 + 3 * (size_t)10061824);
    // [134946816, 191791104): region R — xhi/xlo/wq (early) aliased by yhi/ylo (late)
    char* R = w + 134946816;
    ushort_t* xhi = (ushort_t*)R;
    ushort_t* xlo = (ushort_t*)(R + 9469952);
    ushort_t* wqh = (ushort_t*)(R + 18939904);
    ushort_t* wql = (ushort_t*)(R + 19595264);
    ushort_t* yhi = (ushort_t*)R;                         // alias (after k_qkv done)
    ushort_t* ylo = (ushort_t*)(R + 28422144);

    k_cvt_x<<<dim3(4624), 256, 0, stream>>>((const float4*)x, (ushort4*)xhi, (ushort4*)xlo);
    k_cvt_wqkv<<<dim3(1280), 256, 0, stream>>>(Wqkv, wqh, wql);
    k_gemm<128, 128, 256, 0><<<dim3(10, 145), 256, 0, stream>>>(xhi, xlo, wqh, wql, M, qkv5);
    k_scores<<<dim3(512 * 17), 256, 0, stream>>>(qkv5, A_s, A_v, adjS, adjV,
                                                 attS, attV, attS2, attV2);
    k_xvs_xvv<<<dim3(512), 256, 0, stream>>>(qkv5, attS2, attV2, yhi, ylo);
    k_xvsv<<<dim3(512), 256, 0, stream>>>(qkv5, attS, attV, yhi, ylo);
    k_cvt_wp<<<dim3(256), 256, 0, stream>>>(Wp, wph, wpl);   // into dead qkv5 region
    k_gemm<128, 64, 768, 1><<<dim3(4, 145), 256, 0, stream>>>(yhi, ylo, wph, wpl, bp, out);
}